// Round 1
// baseline (1353.347 us; speedup 1.0000x reference)
//
#include <hip/hip_runtime.h>

#define N_NODES_C 100000
#define N_EDGES_C 1600000

// ---------------------------------------------------------------------------
// GEMM: out[n][64] = in[n][K] @ W[K][64]
// Block = 256 threads = 4 waves; each wave owns one row (wave-uniform row),
// each lane owns one output channel. W staged in LDS (<=32 KB).
// ---------------------------------------------------------------------------
template <int K>
__global__ __launch_bounds__(256) void gemm64_kernel(
    const float* __restrict__ in, const float* __restrict__ W,
    float* __restrict__ out, int n_rows) {
  __shared__ float Ws[K * 64];
  for (int i = threadIdx.x; i < K * 64; i += 256) Ws[i] = W[i];
  __syncthreads();

  int row = blockIdx.x * 4 + (threadIdx.x >> 6);
  int c = threadIdx.x & 63;
  if (row >= n_rows) return;

  const float* xr = in + (size_t)row * K;
  float sum = 0.f;
#pragma unroll 16
  for (int k = 0; k < K; ++k) {
    sum = fmaf(xr[k], Ws[k * 64 + c], sum);
  }
  out[(size_t)row * 64 + c] = sum;
}

// ---------------------------------------------------------------------------
// Edge scatter: for each edge e, agg[dst[e]][c] += h[src[e]][c]
// Thread = (edge, channel); each 64-lane wave handles one edge (coalesced
// 256B gather + coalesced 256B atomic-add).
// ---------------------------------------------------------------------------
__global__ __launch_bounds__(256) void scatter_kernel(
    const float* __restrict__ h, const int* __restrict__ src,
    const int* __restrict__ dst, float* __restrict__ agg, int n_edges) {
  long long idx = (long long)blockIdx.x * 256 + threadIdx.x;
  int e = (int)(idx >> 6);
  int c = (int)(idx & 63);
  if (e >= n_edges) return;
  int s = src[e];
  int d = dst[e];
  atomicAdd(&agg[(size_t)d * 64 + c], h[(size_t)s * 64 + c]);
}

// ---------------------------------------------------------------------------
// out[i] = relu(in[i] + b[i % 64])   (n = N_NODES*64)
// ---------------------------------------------------------------------------
__global__ __launch_bounds__(256) void bias_relu_kernel(
    const float* __restrict__ in, const float* __restrict__ b,
    float* __restrict__ out, int n) {
  int idx = blockIdx.x * 256 + threadIdx.x;
  if (idx >= n) return;
  out[idx] = fmaxf(in[idx] + b[idx & 63], 0.f);
}

extern "C" void kernel_launch(void* const* d_in, const int* in_sizes, int n_in,
                              void* d_out, int out_size, void* d_ws,
                              size_t ws_size, hipStream_t stream) {
  const float* x = (const float*)d_in[0];
  const int* src = (const int*)d_in[1];
  const int* dst = (const int*)d_in[2];
  const float* W1 = (const float*)d_in[3];
  const float* b1 = (const float*)d_in[4];
  const float* W2 = (const float*)d_in[5];
  const float* b2 = (const float*)d_in[6];
  const float* W3 = (const float*)d_in[7];
  const float* b3 = (const float*)d_in[8];
  float* out = (float*)d_out;

  const int N = N_NODES_C;
  const int E = N_EDGES_C;
  const size_t feat_bytes = (size_t)N * 64 * sizeof(float);  // 25.6 MB

  float* A = (float*)d_ws;
  float* B = (float*)((char*)d_ws + feat_bytes);

  const int gemm_grid = (N + 3) / 4;
  const int scat_grid = (int)(((long long)E * 64 + 255) / 256);
  const int ew_grid = (N * 64 + 255) / 256;

  // ---- Layer 1: h = x @ W1 ; agg = scatter ; a = relu(agg + b1) ----
  gemm64_kernel<128><<<gemm_grid, 256, 0, stream>>>(x, W1, A, N);
  hipMemsetAsync(B, 0, feat_bytes, stream);
  scatter_kernel<<<scat_grid, 256, 0, stream>>>(A, src, dst, B, E);
  bias_relu_kernel<<<ew_grid, 256, 0, stream>>>(B, b1, A, N * 64);

  // ---- Layer 2 ----
  gemm64_kernel<64><<<gemm_grid, 256, 0, stream>>>(A, W2, B, N);
  hipMemsetAsync(A, 0, feat_bytes, stream);
  scatter_kernel<<<scat_grid, 256, 0, stream>>>(B, src, dst, A, E);
  bias_relu_kernel<<<ew_grid, 256, 0, stream>>>(A, b2, B, N * 64);

  // ---- Layer 3 (into d_out) ----
  gemm64_kernel<64><<<gemm_grid, 256, 0, stream>>>(B, W3, A, N);
  hipMemsetAsync(out, 0, feat_bytes, stream);
  scatter_kernel<<<scat_grid, 256, 0, stream>>>(A, src, dst, out, E);
  bias_relu_kernel<<<ew_grid, 256, 0, stream>>>(out, b3, out, N * 64);
}

// Round 2
// 656.658 us; speedup vs baseline: 2.0610x; 2.0610x over previous
//
#include <hip/hip_runtime.h>

#define N_NODES_C 100000
#define N_EDGES_C 1600000
#define SCAN_B 256

// ---------------------------------------------------------------------------
// GEMM: out[n][64] = in[n][K] @ W[K][64]
// Block = 256 threads = 4 waves; each wave owns one row, lane = out channel.
// W staged in LDS; row read as float4 broadcast (4 FMAs per load).
// ---------------------------------------------------------------------------
template <int K>
__global__ __launch_bounds__(256) void gemm64_kernel(
    const float* __restrict__ in, const float* __restrict__ W,
    float* __restrict__ out, int n_rows) {
  __shared__ float Ws[K * 64];
  for (int i = threadIdx.x; i < K * 64; i += 256) Ws[i] = W[i];
  __syncthreads();

  int row = blockIdx.x * 4 + (threadIdx.x >> 6);
  int c = threadIdx.x & 63;
  if (row >= n_rows) return;

  const float4* xr4 = (const float4*)(in + (size_t)row * K);
  float sum = 0.f;
#pragma unroll
  for (int k4 = 0; k4 < K / 4; ++k4) {
    float4 v = xr4[k4];
    sum = fmaf(v.x, Ws[(k4 * 4 + 0) * 64 + c], sum);
    sum = fmaf(v.y, Ws[(k4 * 4 + 1) * 64 + c], sum);
    sum = fmaf(v.z, Ws[(k4 * 4 + 2) * 64 + c], sum);
    sum = fmaf(v.w, Ws[(k4 * 4 + 3) * 64 + c], sum);
  }
  out[(size_t)row * 64 + c] = sum;
}

// ---------------------------------------------------------------------------
// CSR build: histogram -> 2-level exclusive scan -> bucket fill
// ---------------------------------------------------------------------------
__global__ __launch_bounds__(256) void hist_kernel(
    const int* __restrict__ dst, int* __restrict__ cnt, int n_edges) {
  int i = blockIdx.x * 256 + threadIdx.x;
  if (i < n_edges) atomicAdd(&cnt[dst[i]], 1);
}

__global__ __launch_bounds__(SCAN_B) void block_sum_kernel(
    const int* __restrict__ cnt, int* __restrict__ bsum, int n) {
  __shared__ int lds[SCAN_B];
  int i = blockIdx.x * SCAN_B + threadIdx.x;
  lds[threadIdx.x] = (i < n) ? cnt[i] : 0;
  __syncthreads();
  for (int s = SCAN_B / 2; s > 0; s >>= 1) {
    if (threadIdx.x < s) lds[threadIdx.x] += lds[threadIdx.x + s];
    __syncthreads();
  }
  if (threadIdx.x == 0) bsum[blockIdx.x] = lds[0];
}

__global__ __launch_bounds__(512) void scan_bsums_kernel(
    int* __restrict__ bsum, int nb) {
  __shared__ int lds[512];
  int v = (threadIdx.x < nb) ? bsum[threadIdx.x] : 0;
  lds[threadIdx.x] = v;
  __syncthreads();
  for (int off = 1; off < 512; off <<= 1) {
    int t = (threadIdx.x >= off) ? lds[threadIdx.x - off] : 0;
    __syncthreads();
    lds[threadIdx.x] += t;
    __syncthreads();
  }
  if (threadIdx.x < nb) bsum[threadIdx.x] = lds[threadIdx.x] - v;  // exclusive
}

__global__ __launch_bounds__(SCAN_B) void scan_final_kernel(
    const int* __restrict__ cnt, const int* __restrict__ bsum,
    int* __restrict__ row_ptr, int* __restrict__ cursor, int n, int total) {
  __shared__ int lds[SCAN_B];
  int i = blockIdx.x * SCAN_B + threadIdx.x;
  int v = (i < n) ? cnt[i] : 0;
  lds[threadIdx.x] = v;
  __syncthreads();
  for (int off = 1; off < SCAN_B; off <<= 1) {
    int t = (threadIdx.x >= off) ? lds[threadIdx.x - off] : 0;
    __syncthreads();
    lds[threadIdx.x] += t;
    __syncthreads();
  }
  int excl = lds[threadIdx.x] - v + bsum[blockIdx.x];
  if (i < n) {
    row_ptr[i] = excl;
    cursor[i] = excl;
  }
  if (i == n - 1) row_ptr[n] = total;
}

__global__ __launch_bounds__(256) void fill_kernel(
    const int* __restrict__ src, const int* __restrict__ dst,
    int* __restrict__ cursor, int* __restrict__ col, int n_edges) {
  int i = blockIdx.x * 256 + threadIdx.x;
  if (i < n_edges) {
    int pos = atomicAdd(&cursor[dst[i]], 1);
    col[pos] = src[i];
  }
}

// ---------------------------------------------------------------------------
// Pull aggregation + bias + ReLU: out[n][c] = relu(b[c] + sum_e h[col[e]][c])
// One wave per node, lane = channel. 256B coalesced gather per edge.
// ---------------------------------------------------------------------------
__global__ __launch_bounds__(256) void agg_kernel(
    const float* __restrict__ h, const int* __restrict__ row_ptr,
    const int* __restrict__ col, const float* __restrict__ bias,
    float* __restrict__ out, int n_nodes) {
  int node = blockIdx.x * 4 + (threadIdx.x >> 6);
  int c = threadIdx.x & 63;
  if (node >= n_nodes) return;
  int beg = row_ptr[node];
  int end = row_ptr[node + 1];
  float sum = bias[c];
  int e = beg;
  for (; e + 4 <= end; e += 4) {
    int s0 = col[e + 0];
    int s1 = col[e + 1];
    int s2 = col[e + 2];
    int s3 = col[e + 3];
    float v0 = h[(size_t)s0 * 64 + c];
    float v1 = h[(size_t)s1 * 64 + c];
    float v2 = h[(size_t)s2 * 64 + c];
    float v3 = h[(size_t)s3 * 64 + c];
    sum += v0 + v1 + v2 + v3;
  }
  for (; e < end; ++e) sum += h[(size_t)col[e] * 64 + c];
  out[(size_t)node * 64 + c] = fmaxf(sum, 0.f);
}

extern "C" void kernel_launch(void* const* d_in, const int* in_sizes, int n_in,
                              void* d_out, int out_size, void* d_ws,
                              size_t ws_size, hipStream_t stream) {
  const float* x = (const float*)d_in[0];
  const int* src = (const int*)d_in[1];
  const int* dst = (const int*)d_in[2];
  const float* W1 = (const float*)d_in[3];
  const float* b1 = (const float*)d_in[4];
  const float* W2 = (const float*)d_in[5];
  const float* b2 = (const float*)d_in[6];
  const float* W3 = (const float*)d_in[7];
  const float* b3 = (const float*)d_in[8];
  float* out = (float*)d_out;

  const int N = N_NODES_C;
  const int E = N_EDGES_C;

  // Workspace layout
  char* ws = (char*)d_ws;
  int* row_ptr = (int*)(ws + 0);              // (N+1) ints, reserve 1 MB
  int* cnt = (int*)(ws + (1 << 20));          // N ints, reserve 1 MB
  int* cursor = (int*)(ws + (2 << 20));       // N ints, reserve 1 MB
  int* bsum = (int*)(ws + (3 << 20));         // <=512 ints, reserve 1 MB
  int* col = (int*)(ws + (4 << 20));          // E ints (6.4 MB), reserve 7 MB
  float* A = (float*)(ws + (11u << 20));      // N*64 floats (25.6 MB)

  const int nb = (N + SCAN_B - 1) / SCAN_B;   // 391
  const int eg = (E + 255) / 256;             // 6250
  const int gemm_grid = (N + 3) / 4;
  const int agg_grid = (N + 3) / 4;

  // ---- CSR build (dst -> sorted edge buckets of src) ----
  hipMemsetAsync(cnt, 0, (size_t)N * sizeof(int), stream);
  hist_kernel<<<eg, 256, 0, stream>>>(dst, cnt, E);
  block_sum_kernel<<<nb, SCAN_B, 0, stream>>>(cnt, bsum, N);
  scan_bsums_kernel<<<1, 512, 0, stream>>>(bsum, nb);
  scan_final_kernel<<<nb, SCAN_B, 0, stream>>>(cnt, bsum, row_ptr, cursor, N, E);
  fill_kernel<<<eg, 256, 0, stream>>>(src, dst, cursor, col, E);

  // ---- Layer 1: A = x @ W1 ; d_out = relu(agg(A) + b1) ----
  gemm64_kernel<128><<<gemm_grid, 256, 0, stream>>>(x, W1, A, N);
  agg_kernel<<<agg_grid, 256, 0, stream>>>(A, row_ptr, col, b1, out, N);

  // ---- Layer 2: A = d_out @ W2 ; d_out = relu(agg(A) + b2) ----
  gemm64_kernel<64><<<gemm_grid, 256, 0, stream>>>(out, W2, A, N);
  agg_kernel<<<agg_grid, 256, 0, stream>>>(A, row_ptr, col, b2, out, N);

  // ---- Layer 3: A = d_out @ W3 ; d_out = relu(agg(A) + b3) ----
  gemm64_kernel<64><<<gemm_grid, 256, 0, stream>>>(out, W3, A, N);
  agg_kernel<<<agg_grid, 256, 0, stream>>>(A, row_ptr, col, b3, out, N);
}

// Round 3
// 590.126 us; speedup vs baseline: 2.2933x; 1.1127x over previous
//
#include <hip/hip_runtime.h>

#define N_NODES_C 100000
#define N_EDGES_C 1600000
#define SCAN_B 256

// ---------------------------------------------------------------------------
// GEMM: out[n][64] = in[n][K] @ W[K][64]
// Block = 256 threads = 4 waves; each wave owns 8 rows, lane = out channel.
// W staged in LDS [K][64] (conflict-free: consecutive lanes -> consecutive
// banks). Per k: 1 ds_read_b32 amortized over 8 FMAs (8 rows). Row bases are
// readfirstlane'd so x-row reads take the scalar/SMEM path.
// ---------------------------------------------------------------------------
template <int K>
__global__ __launch_bounds__(256) void gemm64_kernel(
    const float* __restrict__ in, const float* __restrict__ W,
    float* __restrict__ out, int n_rows) {
  __shared__ float Ws[K * 64];
  for (int i = threadIdx.x; i < K * 64; i += 256) Ws[i] = W[i];
  __syncthreads();

  int wave = threadIdx.x >> 6;
  int c = threadIdx.x & 63;
  int row0 = __builtin_amdgcn_readfirstlane((blockIdx.x * 4 + wave) * 8);
  if (row0 >= n_rows) return;

  if (row0 + 8 <= n_rows) {
    const float* r0 = in + (size_t)row0 * K;
    float s0 = 0, s1 = 0, s2 = 0, s3 = 0, s4 = 0, s5 = 0, s6 = 0, s7 = 0;
#pragma unroll 8
    for (int k = 0; k < K; ++k) {
      float w = Ws[k * 64 + c];
      s0 = fmaf(r0[0 * K + k], w, s0);
      s1 = fmaf(r0[1 * K + k], w, s1);
      s2 = fmaf(r0[2 * K + k], w, s2);
      s3 = fmaf(r0[3 * K + k], w, s3);
      s4 = fmaf(r0[4 * K + k], w, s4);
      s5 = fmaf(r0[5 * K + k], w, s5);
      s6 = fmaf(r0[6 * K + k], w, s6);
      s7 = fmaf(r0[7 * K + k], w, s7);
    }
    float* o = out + (size_t)row0 * 64 + c;
    o[0 * 64] = s0; o[1 * 64] = s1; o[2 * 64] = s2; o[3 * 64] = s3;
    o[4 * 64] = s4; o[5 * 64] = s5; o[6 * 64] = s6; o[7 * 64] = s7;
  } else {
    for (int r = row0; r < n_rows; ++r) {
      const float* xr = in + (size_t)r * K;
      float sum = 0.f;
      for (int k = 0; k < K; ++k) sum = fmaf(xr[k], Ws[k * 64 + c], sum);
      out[(size_t)r * 64 + c] = sum;
    }
  }
}

// ---------------------------------------------------------------------------
// CSR build: histogram -> 2-level exclusive scan -> bucket fill
// ---------------------------------------------------------------------------
__global__ __launch_bounds__(256) void hist_kernel(
    const int* __restrict__ dst, int* __restrict__ cnt, int n_edges) {
  int i = blockIdx.x * 256 + threadIdx.x;
  if (i < n_edges) atomicAdd(&cnt[dst[i]], 1);
}

__global__ __launch_bounds__(SCAN_B) void block_sum_kernel(
    const int* __restrict__ cnt, int* __restrict__ bsum, int n) {
  __shared__ int lds[SCAN_B];
  int i = blockIdx.x * SCAN_B + threadIdx.x;
  lds[threadIdx.x] = (i < n) ? cnt[i] : 0;
  __syncthreads();
  for (int s = SCAN_B / 2; s > 0; s >>= 1) {
    if (threadIdx.x < s) lds[threadIdx.x] += lds[threadIdx.x + s];
    __syncthreads();
  }
  if (threadIdx.x == 0) bsum[blockIdx.x] = lds[0];
}

__global__ __launch_bounds__(512) void scan_bsums_kernel(
    int* __restrict__ bsum, int nb) {
  __shared__ int lds[512];
  int v = (threadIdx.x < nb) ? bsum[threadIdx.x] : 0;
  lds[threadIdx.x] = v;
  __syncthreads();
  for (int off = 1; off < 512; off <<= 1) {
    int t = (threadIdx.x >= off) ? lds[threadIdx.x - off] : 0;
    __syncthreads();
    lds[threadIdx.x] += t;
    __syncthreads();
  }
  if (threadIdx.x < nb) bsum[threadIdx.x] = lds[threadIdx.x] - v;  // exclusive
}

__global__ __launch_bounds__(SCAN_B) void scan_final_kernel(
    const int* __restrict__ cnt, const int* __restrict__ bsum,
    int* __restrict__ row_ptr, int* __restrict__ cursor, int n, int total) {
  __shared__ int lds[SCAN_B];
  int i = blockIdx.x * SCAN_B + threadIdx.x;
  int v = (i < n) ? cnt[i] : 0;
  lds[threadIdx.x] = v;
  __syncthreads();
  for (int off = 1; off < SCAN_B; off <<= 1) {
    int t = (threadIdx.x >= off) ? lds[threadIdx.x - off] : 0;
    __syncthreads();
    lds[threadIdx.x] += t;
    __syncthreads();
  }
  int excl = lds[threadIdx.x] - v + bsum[blockIdx.x];
  if (i < n) {
    row_ptr[i] = excl;
    cursor[i] = excl;
  }
  if (i == n - 1) row_ptr[n] = total;
}

__global__ __launch_bounds__(256) void fill_kernel(
    const int* __restrict__ src, const int* __restrict__ dst,
    int* __restrict__ cursor, int* __restrict__ col, int n_edges) {
  int i = blockIdx.x * 256 + threadIdx.x;
  if (i < n_edges) {
    int pos = atomicAdd(&cursor[dst[i]], 1);
    col[pos] = src[i];
  }
}

// ---------------------------------------------------------------------------
// Pull aggregation + bias + ReLU: out[n][c] = relu(b[c] + sum_e h[col[e]][c])
// One wave per node, lane = channel. 256B coalesced gather per edge.
// ---------------------------------------------------------------------------
__global__ __launch_bounds__(256) void agg_kernel(
    const float* __restrict__ h, const int* __restrict__ row_ptr,
    const int* __restrict__ col, const float* __restrict__ bias,
    float* __restrict__ out, int n_nodes) {
  int node = blockIdx.x * 4 + (threadIdx.x >> 6);
  int c = threadIdx.x & 63;
  if (node >= n_nodes) return;
  int beg = row_ptr[node];
  int end = row_ptr[node + 1];
  float sum = bias[c];
  int e = beg;
  for (; e + 4 <= end; e += 4) {
    int s0 = col[e + 0];
    int s1 = col[e + 1];
    int s2 = col[e + 2];
    int s3 = col[e + 3];
    float v0 = h[(size_t)s0 * 64 + c];
    float v1 = h[(size_t)s1 * 64 + c];
    float v2 = h[(size_t)s2 * 64 + c];
    float v3 = h[(size_t)s3 * 64 + c];
    sum += v0 + v1 + v2 + v3;
  }
  for (; e < end; ++e) sum += h[(size_t)col[e] * 64 + c];
  out[(size_t)node * 64 + c] = fmaxf(sum, 0.f);
}

extern "C" void kernel_launch(void* const* d_in, const int* in_sizes, int n_in,
                              void* d_out, int out_size, void* d_ws,
                              size_t ws_size, hipStream_t stream) {
  const float* x = (const float*)d_in[0];
  const int* src = (const int*)d_in[1];
  const int* dst = (const int*)d_in[2];
  const float* W1 = (const float*)d_in[3];
  const float* b1 = (const float*)d_in[4];
  const float* W2 = (const float*)d_in[5];
  const float* b2 = (const float*)d_in[6];
  const float* W3 = (const float*)d_in[7];
  const float* b3 = (const float*)d_in[8];
  float* out = (float*)d_out;

  const int N = N_NODES_C;
  const int E = N_EDGES_C;

  // Workspace layout
  char* ws = (char*)d_ws;
  int* row_ptr = (int*)(ws + 0);              // (N+1) ints, reserve 1 MB
  int* cnt = (int*)(ws + (1 << 20));          // N ints, reserve 1 MB
  int* cursor = (int*)(ws + (2 << 20));       // N ints, reserve 1 MB
  int* bsum = (int*)(ws + (3 << 20));         // <=512 ints, reserve 1 MB
  int* col = (int*)(ws + (4 << 20));          // E ints (6.4 MB), reserve 7 MB
  float* A = (float*)(ws + (11u << 20));      // N*64 floats (25.6 MB)

  const int nb = (N + SCAN_B - 1) / SCAN_B;   // 391
  const int eg = (E + 255) / 256;             // 6250
  const int gemm_grid = (N + 31) / 32;        // 4 waves x 8 rows per block
  const int agg_grid = (N + 3) / 4;

  // ---- CSR build (dst -> edge buckets of src) ----
  hipMemsetAsync(cnt, 0, (size_t)N * sizeof(int), stream);
  hist_kernel<<<eg, 256, 0, stream>>>(dst, cnt, E);
  block_sum_kernel<<<nb, SCAN_B, 0, stream>>>(cnt, bsum, N);
  scan_bsums_kernel<<<1, 512, 0, stream>>>(bsum, nb);
  scan_final_kernel<<<nb, SCAN_B, 0, stream>>>(cnt, bsum, row_ptr, cursor, N, E);
  fill_kernel<<<eg, 256, 0, stream>>>(src, dst, cursor, col, E);

  // ---- Layer 1: A = x @ W1 ; d_out = relu(agg(A) + b1) ----
  gemm64_kernel<128><<<gemm_grid, 256, 0, stream>>>(x, W1, A, N);
  agg_kernel<<<agg_grid, 256, 0, stream>>>(A, row_ptr, col, b1, out, N);

  // ---- Layer 2: A = d_out @ W2 ; d_out = relu(agg(A) + b2) ----
  gemm64_kernel<64><<<gemm_grid, 256, 0, stream>>>(out, W2, A, N);
  agg_kernel<<<agg_grid, 256, 0, stream>>>(A, row_ptr, col, b2, out, N);

  // ---- Layer 3: A = d_out @ W3 ; d_out = relu(agg(A) + b3) ----
  gemm64_kernel<64><<<gemm_grid, 256, 0, stream>>>(out, W3, A, N);
  agg_kernel<<<agg_grid, 256, 0, stream>>>(A, row_ptr, col, b3, out, N);
}

// Round 4
// 329.939 us; speedup vs baseline: 4.1018x; 1.7886x over previous
//
#include <hip/hip_runtime.h>

#define N_NODES_C 100000
#define N_EDGES_C 1600000
#define SCAN_B 256

typedef short short8 __attribute__((ext_vector_type(8)));
typedef float f32x4 __attribute__((ext_vector_type(4)));

// float -> bf16 bits (RNE)
__device__ __forceinline__ short f2bf(float f) {
  unsigned u = __builtin_bit_cast(unsigned, f);
  unsigned r = (u + 0x7FFFu + ((u >> 16) & 1u)) >> 16;
  return (short)r;
}
// bf16 bits in low/high half of u32 -> float
__device__ __forceinline__ float bf_lo(unsigned u) {
  return __builtin_bit_cast(float, u << 16);
}
__device__ __forceinline__ float bf_hi(unsigned u) {
  return __builtin_bit_cast(float, u & 0xFFFF0000u);
}

// ---------------------------------------------------------------------------
// MFMA GEMM: out[n][64] = in[n][K] @ W[K][64]
// Block = 4 waves, each wave computes a 16x64 output tile via 4 n-tiles of
// mfma_f32_16x16x32_bf16. No LDS. W fragments held in registers
// (loop-invariant). A streamed from global (fp32 converted, or bf16 direct).
// Layouts (verified, learn_hip m89/m91): A: row=lane&15, k=(lane>>4)*8+j;
// B: col=lane&15, k=(lane>>4)*8+j; C/D: col=lane&15, row=(lane>>4)*4+reg.
// ---------------------------------------------------------------------------
template <int K, bool IN_BF, bool OUT_BF>
__global__ __launch_bounds__(256) void mfma_gemm64(
    const void* __restrict__ in_, const float* __restrict__ W,
    void* __restrict__ out_, int n_rows) {
  constexpr int KS = K / 32;
  int wave = threadIdx.x >> 6;
  int lane = threadIdx.x & 63;
  int row0 = (blockIdx.x * 4 + wave) * 16;
  if (row0 >= n_rows) return;  // n_rows % 16 == 0, so surviving tiles are full

  int lrow = lane & 15;        // A row / C col / B col
  int lk = (lane >> 4) * 8;    // k base within the 32-wide k-step

  // B fragments: [k-step][n-tile]
  short8 bfrag[KS][4];
#pragma unroll
  for (int ks = 0; ks < KS; ++ks)
#pragma unroll
    for (int nt = 0; nt < 4; ++nt) {
      short8 b;
#pragma unroll
      for (int j = 0; j < 8; ++j)
        b[j] = f2bf(W[(size_t)(ks * 32 + lk + j) * 64 + nt * 16 + lrow]);
      bfrag[ks][nt] = b;
    }

  int row = row0 + lrow;
  f32x4 acc[4] = {};
#pragma unroll
  for (int ks = 0; ks < KS; ++ks) {
    short8 a;
    if constexpr (IN_BF) {
      const short* ip = (const short*)in_ + (size_t)row * K + ks * 32 + lk;
      a = *(const short8*)ip;  // 16B aligned
    } else {
      const float* ip = (const float*)in_ + (size_t)row * K + ks * 32 + lk;
      f32x4 v0 = *(const f32x4*)(ip);
      f32x4 v1 = *(const f32x4*)(ip + 4);
#pragma unroll
      for (int j = 0; j < 4; ++j) {
        a[j] = f2bf(v0[j]);
        a[4 + j] = f2bf(v1[j]);
      }
    }
#pragma unroll
    for (int nt = 0; nt < 4; ++nt)
      acc[nt] = __builtin_amdgcn_mfma_f32_16x16x32_bf16(a, bfrag[ks][nt],
                                                        acc[nt], 0, 0, 0);
  }

  int crow = row0 + (lane >> 4) * 4;
#pragma unroll
  for (int nt = 0; nt < 4; ++nt) {
    int ocol = nt * 16 + lrow;
#pragma unroll
    for (int r = 0; r < 4; ++r) {
      if constexpr (OUT_BF)
        ((short*)out_)[(size_t)(crow + r) * 64 + ocol] = f2bf(acc[nt][r]);
      else
        ((float*)out_)[(size_t)(crow + r) * 64 + ocol] = acc[nt][r];
    }
  }
}

// ---------------------------------------------------------------------------
// CSR build: hist (atomic, returns rank) -> 2-level scan -> atomic-free fill
// ---------------------------------------------------------------------------
__global__ __launch_bounds__(256) void hist_rank_kernel(
    const int* __restrict__ dst, int* __restrict__ cnt, int* __restrict__ rank,
    int n_edges) {
  int i = blockIdx.x * 256 + threadIdx.x;
  if (i < n_edges) rank[i] = atomicAdd(&cnt[dst[i]], 1);
}

__global__ __launch_bounds__(SCAN_B) void block_sum_kernel(
    const int* __restrict__ cnt, int* __restrict__ bsum, int n) {
  __shared__ int lds[SCAN_B];
  int i = blockIdx.x * SCAN_B + threadIdx.x;
  lds[threadIdx.x] = (i < n) ? cnt[i] : 0;
  __syncthreads();
  for (int s = SCAN_B / 2; s > 0; s >>= 1) {
    if (threadIdx.x < s) lds[threadIdx.x] += lds[threadIdx.x + s];
    __syncthreads();
  }
  if (threadIdx.x == 0) bsum[blockIdx.x] = lds[0];
}

__global__ __launch_bounds__(512) void scan_bsums_kernel(
    int* __restrict__ bsum, int nb) {
  __shared__ int lds[512];
  int v = (threadIdx.x < nb) ? bsum[threadIdx.x] : 0;
  lds[threadIdx.x] = v;
  __syncthreads();
  for (int off = 1; off < 512; off <<= 1) {
    int t = (threadIdx.x >= off) ? lds[threadIdx.x - off] : 0;
    __syncthreads();
    lds[threadIdx.x] += t;
    __syncthreads();
  }
  if (threadIdx.x < nb) bsum[threadIdx.x] = lds[threadIdx.x] - v;  // exclusive
}

__global__ __launch_bounds__(SCAN_B) void scan_final_kernel(
    const int* __restrict__ cnt, const int* __restrict__ bsum,
    int* __restrict__ row_ptr, int n, int total) {
  __shared__ int lds[SCAN_B];
  int i = blockIdx.x * SCAN_B + threadIdx.x;
  int v = (i < n) ? cnt[i] : 0;
  lds[threadIdx.x] = v;
  __syncthreads();
  for (int off = 1; off < SCAN_B; off <<= 1) {
    int t = (threadIdx.x >= off) ? lds[threadIdx.x - off] : 0;
    __syncthreads();
    lds[threadIdx.x] += t;
    __syncthreads();
  }
  int excl = lds[threadIdx.x] - v + bsum[blockIdx.x];
  if (i < n) row_ptr[i] = excl;
  if (i == n - 1) row_ptr[n] = total;
}

__global__ __launch_bounds__(256) void fill_kernel(
    const int* __restrict__ src, const int* __restrict__ dst,
    const int* __restrict__ rank, const int* __restrict__ row_ptr,
    int* __restrict__ col, int n_edges) {
  int i = blockIdx.x * 256 + threadIdx.x;
  if (i < n_edges) col[row_ptr[dst[i]] + rank[i]] = src[i];
}

// ---------------------------------------------------------------------------
// Pull aggregation + bias + ReLU. h is bf16 [N][64]. One wave per node:
// lane = (edge-parity half) x (channel pair). Each lane loads bf16x2 (u32),
// accumulates fp32, halves combined via shfl_xor(32). Out bf16 or fp32.
// ---------------------------------------------------------------------------
template <bool OUT_BF>
__global__ __launch_bounds__(256) void agg64_kernel(
    const short* __restrict__ h, const int* __restrict__ row_ptr,
    const int* __restrict__ col, const float* __restrict__ bias,
    void* __restrict__ out, int n_nodes) {
  int node = blockIdx.x * 4 + (threadIdx.x >> 6);
  if (node >= n_nodes) return;
  int lane = threadIdx.x & 63;
  int half = lane >> 5;  // which edge of a pair
  int cp = lane & 31;    // channel pair index (channels 2cp, 2cp+1)

  int beg = row_ptr[node];
  int end = row_ptr[node + 1];
  float a0 = 0.f, a1 = 0.f;
  int e = beg + half;
  for (; e + 2 < end; e += 4) {
    int s0 = col[e];
    int s1 = col[e + 2];
    unsigned u0 = *(const unsigned*)(h + (size_t)s0 * 64 + cp * 2);
    unsigned u1 = *(const unsigned*)(h + (size_t)s1 * 64 + cp * 2);
    a0 += bf_lo(u0) + bf_lo(u1);
    a1 += bf_hi(u0) + bf_hi(u1);
  }
  for (; e < end; e += 2) {
    int s = col[e];
    unsigned u = *(const unsigned*)(h + (size_t)s * 64 + cp * 2);
    a0 += bf_lo(u);
    a1 += bf_hi(u);
  }
  a0 += __shfl_xor(a0, 32);
  a1 += __shfl_xor(a1, 32);

  float r0 = fmaxf(a0 + bias[cp * 2 + 0], 0.f);
  float r1 = fmaxf(a1 + bias[cp * 2 + 1], 0.f);
  if (lane < 32) {
    if constexpr (OUT_BF) {
      unsigned pack = (unsigned)(unsigned short)f2bf(r0) |
                      ((unsigned)(unsigned short)f2bf(r1) << 16);
      ((unsigned*)out)[(size_t)node * 32 + cp] = pack;
    } else {
      float2 v;
      v.x = r0;
      v.y = r1;
      ((float2*)out)[(size_t)node * 32 + cp] = v;
    }
  }
}

extern "C" void kernel_launch(void* const* d_in, const int* in_sizes, int n_in,
                              void* d_out, int out_size, void* d_ws,
                              size_t ws_size, hipStream_t stream) {
  const float* x = (const float*)d_in[0];
  const int* src = (const int*)d_in[1];
  const int* dst = (const int*)d_in[2];
  const float* W1 = (const float*)d_in[3];
  const float* b1 = (const float*)d_in[4];
  const float* W2 = (const float*)d_in[5];
  const float* b2 = (const float*)d_in[6];
  const float* W3 = (const float*)d_in[7];
  const float* b3 = (const float*)d_in[8];
  float* out = (float*)d_out;

  const int N = N_NODES_C;
  const int E = N_EDGES_C;

  // Workspace layout (35 MB total; build-time buffers overlap hA region):
  //   [0, 1MB)    row_ptr (N+1 ints)            [persistent]
  //   [1, 9MB)    col (E ints = 6.4MB)          [persistent]
  //   [9, 22MB)   hA (N*64 bf16 = 12.8MB)       [layer phase]
  //     build-phase overlap: cnt @9MB (400KB), bsum @10MB, rank @11MB (6.4MB)
  //   [22, 35MB)  hB (N*64 bf16 = 12.8MB)
  char* ws = (char*)d_ws;
  int* row_ptr = (int*)(ws + 0);
  int* col = (int*)(ws + (1u << 20));
  short* hA = (short*)(ws + (9u << 20));
  int* cnt = (int*)(ws + (9u << 20));
  int* bsum = (int*)(ws + (10u << 20));
  int* rank = (int*)(ws + (11u << 20));
  short* hB = (short*)(ws + (22u << 20));

  const int nb = (N + SCAN_B - 1) / SCAN_B;  // 391
  const int eg = (E + 255) / 256;            // 6250
  const int gemm_grid = (N + 63) / 64;       // 4 waves x 16 rows
  const int agg_grid = (N + 3) / 4;

  // ---- CSR build ----
  hipMemsetAsync(cnt, 0, (size_t)N * sizeof(int), stream);
  hist_rank_kernel<<<eg, 256, 0, stream>>>(dst, cnt, rank, E);
  block_sum_kernel<<<nb, SCAN_B, 0, stream>>>(cnt, bsum, N);
  scan_bsums_kernel<<<1, 512, 0, stream>>>(bsum, nb);
  scan_final_kernel<<<nb, SCAN_B, 0, stream>>>(cnt, bsum, row_ptr, N, E);
  fill_kernel<<<eg, 256, 0, stream>>>(src, dst, rank, row_ptr, col, E);

  // ---- Layer 1: hA = bf16(x @ W1) ; hB = bf16(relu(agg(hA) + b1)) ----
  mfma_gemm64<128, false, true>
      <<<gemm_grid, 256, 0, stream>>>(x, W1, hA, N);
  agg64_kernel<true><<<agg_grid, 256, 0, stream>>>(hA, row_ptr, col, b1, hB, N);

  // ---- Layer 2 ----
  mfma_gemm64<64, true, true>
      <<<gemm_grid, 256, 0, stream>>>(hB, W2, hA, N);
  agg64_kernel<true><<<agg_grid, 256, 0, stream>>>(hA, row_ptr, col, b2, hB, N);

  // ---- Layer 3 (fp32 out) ----
  mfma_gemm64<64, true, true>
      <<<gemm_grid, 256, 0, stream>>>(hB, W3, hA, N);
  agg64_kernel<false><<<agg_grid, 256, 0, stream>>>(hA, row_ptr, col, b3, out, N);
}

// Round 5
// 305.228 us; speedup vs baseline: 4.4339x; 1.0810x over previous
//
#include <hip/hip_runtime.h>

#define N_NODES_C 100000
#define N_EDGES_C 1600000
#define SCAN_B 256

typedef short short8 __attribute__((ext_vector_type(8)));
typedef float f32x4 __attribute__((ext_vector_type(4)));

// float -> bf16 bits (RNE)
__device__ __forceinline__ short f2bf(float f) {
  unsigned u = __builtin_bit_cast(unsigned, f);
  unsigned r = (u + 0x7FFFu + ((u >> 16) & 1u)) >> 16;
  return (short)r;
}
// bf16 bits in low/high half of u32 -> float
__device__ __forceinline__ float bf_lo(unsigned u) {
  return __builtin_bit_cast(float, u << 16);
}
__device__ __forceinline__ float bf_hi(unsigned u) {
  return __builtin_bit_cast(float, u & 0xFFFF0000u);
}

// ---------------------------------------------------------------------------
// MFMA GEMM body: out[n][64] = in[n][K] @ W[K][64]
// 4 waves/block, each wave computes a 16x64 tile via 4 n-tiles of
// mfma_f32_16x16x32_bf16. No LDS; W fragments in registers (loop-invariant).
// Layouts (verified, learn_hip m89/m91): A: row=lane&15, k=(lane>>4)*8+j;
// B: col=lane&15, k=(lane>>4)*8+j; C/D: col=lane&15, row=(lane>>4)*4+reg.
// ---------------------------------------------------------------------------
template <int K, bool IN_BF, bool OUT_BF>
__device__ __forceinline__ void gemm64_body(
    int gblock, const void* __restrict__ in_, const float* __restrict__ W,
    void* __restrict__ out_, int n_rows) {
  constexpr int KS = K / 32;
  int wave = threadIdx.x >> 6;
  int lane = threadIdx.x & 63;
  int row0 = (gblock * 4 + wave) * 16;
  if (row0 >= n_rows) return;  // n_rows % 16 == 0 -> surviving tiles full

  int lrow = lane & 15;
  int lk = (lane >> 4) * 8;

  short8 bfrag[KS][4];
#pragma unroll
  for (int ks = 0; ks < KS; ++ks)
#pragma unroll
    for (int nt = 0; nt < 4; ++nt) {
      short8 b;
#pragma unroll
      for (int j = 0; j < 8; ++j)
        b[j] = f2bf(W[(size_t)(ks * 32 + lk + j) * 64 + nt * 16 + lrow]);
      bfrag[ks][nt] = b;
    }

  int row = row0 + lrow;
  f32x4 acc[4] = {};
#pragma unroll
  for (int ks = 0; ks < KS; ++ks) {
    short8 a;
    if constexpr (IN_BF) {
      const short* ip = (const short*)in_ + (size_t)row * K + ks * 32 + lk;
      a = *(const short8*)ip;
    } else {
      const float* ip = (const float*)in_ + (size_t)row * K + ks * 32 + lk;
      f32x4 v0 = *(const f32x4*)(ip);
      f32x4 v1 = *(const f32x4*)(ip + 4);
#pragma unroll
      for (int j = 0; j < 4; ++j) {
        a[j] = f2bf(v0[j]);
        a[4 + j] = f2bf(v1[j]);
      }
    }
#pragma unroll
    for (int nt = 0; nt < 4; ++nt)
      acc[nt] = __builtin_amdgcn_mfma_f32_16x16x32_bf16(a, bfrag[ks][nt],
                                                        acc[nt], 0, 0, 0);
  }

  int crow = row0 + (lane >> 4) * 4;
#pragma unroll
  for (int nt = 0; nt < 4; ++nt) {
    int ocol = nt * 16 + lrow;
#pragma unroll
    for (int r = 0; r < 4; ++r) {
      if constexpr (OUT_BF)
        ((short*)out_)[(size_t)(crow + r) * 64 + ocol] = f2bf(acc[nt][r]);
      else
        ((float*)out_)[(size_t)(crow + r) * 64 + ocol] = acc[nt][r];
    }
  }
}

template <int K, bool IN_BF, bool OUT_BF>
__global__ __launch_bounds__(256) void mfma_gemm64(
    const void* __restrict__ in_, const float* __restrict__ W,
    void* __restrict__ out_, int n_rows) {
  gemm64_body<K, IN_BF, OUT_BF>(blockIdx.x, in_, W, out_, n_rows);
}

// ---------------------------------------------------------------------------
// Fused: blocks [0, gemm_blocks) do GEMM1 (x @ W1 -> hA, fp32 in, bf16 out);
// blocks [gemm_blocks, ...) do the edge histogram + rank. Independent data;
// hist is atomic-unit-bound so sharing CUs with the streaming gemm is ~free.
// ---------------------------------------------------------------------------
__global__ __launch_bounds__(256) void hist_gemm1_kernel(
    const float* __restrict__ x, const float* __restrict__ W1,
    short* __restrict__ hA, int n_rows, int gemm_blocks,
    const int* __restrict__ dst, int* __restrict__ cnt, int* __restrict__ rank,
    int n_edges) {
  int b = (int)blockIdx.x;
  if (b < gemm_blocks) {
    gemm64_body<128, false, true>(b, x, W1, hA, n_rows);
  } else {
    int i = (b - gemm_blocks) * 256 + threadIdx.x;
    if (i < n_edges) rank[i] = atomicAdd(&cnt[dst[i]], 1);
  }
}

// ---------------------------------------------------------------------------
// CSR build: scans + atomic-free fill
// ---------------------------------------------------------------------------
__global__ __launch_bounds__(SCAN_B) void block_sum_kernel(
    const int* __restrict__ cnt, int* __restrict__ bsum, int n) {
  __shared__ int lds[SCAN_B];
  int i = blockIdx.x * SCAN_B + threadIdx.x;
  lds[threadIdx.x] = (i < n) ? cnt[i] : 0;
  __syncthreads();
  for (int s = SCAN_B / 2; s > 0; s >>= 1) {
    if (threadIdx.x < s) lds[threadIdx.x] += lds[threadIdx.x + s];
    __syncthreads();
  }
  if (threadIdx.x == 0) bsum[blockIdx.x] = lds[0];
}

__global__ __launch_bounds__(512) void scan_bsums_kernel(
    int* __restrict__ bsum, int nb) {
  __shared__ int lds[512];
  int v = (threadIdx.x < nb) ? bsum[threadIdx.x] : 0;
  lds[threadIdx.x] = v;
  __syncthreads();
  for (int off = 1; off < 512; off <<= 1) {
    int t = (threadIdx.x >= off) ? lds[threadIdx.x - off] : 0;
    __syncthreads();
    lds[threadIdx.x] += t;
    __syncthreads();
  }
  if (threadIdx.x < nb) bsum[threadIdx.x] = lds[threadIdx.x] - v;  // exclusive
}

__global__ __launch_bounds__(SCAN_B) void scan_final_kernel(
    const int* __restrict__ cnt, const int* __restrict__ bsum,
    int* __restrict__ row_ptr, int n, int total) {
  __shared__ int lds[SCAN_B];
  int i = blockIdx.x * SCAN_B + threadIdx.x;
  int v = (i < n) ? cnt[i] : 0;
  lds[threadIdx.x] = v;
  __syncthreads();
  for (int off = 1; off < SCAN_B; off <<= 1) {
    int t = (threadIdx.x >= off) ? lds[threadIdx.x - off] : 0;
    __syncthreads();
    lds[threadIdx.x] += t;
    __syncthreads();
  }
  int excl = lds[threadIdx.x] - v + bsum[blockIdx.x];
  if (i < n) row_ptr[i] = excl;
  if (i == n - 1) row_ptr[n] = total;
}

// 4 edges per thread, int4 loads, 4 independent scattered stores in flight.
__global__ __launch_bounds__(256) void fill_kernel(
    const int* __restrict__ src, const int* __restrict__ dst,
    const int* __restrict__ rank, const int* __restrict__ row_ptr,
    int* __restrict__ col, int n_edges) {
  int i4 = (blockIdx.x * 256 + threadIdx.x) * 4;
  if (i4 + 3 < n_edges) {
    int4 d = *(const int4*)(dst + i4);
    int4 r = *(const int4*)(rank + i4);
    int4 s = *(const int4*)(src + i4);
    col[row_ptr[d.x] + r.x] = s.x;
    col[row_ptr[d.y] + r.y] = s.y;
    col[row_ptr[d.z] + r.z] = s.z;
    col[row_ptr[d.w] + r.w] = s.w;
  } else {
    for (int i = i4; i < n_edges; ++i)
      col[row_ptr[dst[i]] + rank[i]] = src[i];
  }
}

// ---------------------------------------------------------------------------
// Pull aggregation + bias + ReLU. h bf16 [N][64]. Wave per node; lane =
// (edge-parity half) x (channel pair). 8 edges/iter, two accumulator pairs.
// ---------------------------------------------------------------------------
template <bool OUT_BF>
__global__ __launch_bounds__(256) void agg64_kernel(
    const short* __restrict__ h, const int* __restrict__ row_ptr,
    const int* __restrict__ col, const float* __restrict__ bias,
    void* __restrict__ out, int n_nodes) {
  int node = blockIdx.x * 4 + (threadIdx.x >> 6);
  if (node >= n_nodes) return;
  int lane = threadIdx.x & 63;
  int half = lane >> 5;
  int cp = lane & 31;

  int beg = row_ptr[node];
  int end = row_ptr[node + 1];
  float a0 = 0.f, a1 = 0.f, b0 = 0.f, b1 = 0.f;
  int e = beg + half;
  for (; e + 6 < end; e += 8) {
    int s0 = col[e];
    int s1 = col[e + 2];
    int s2 = col[e + 4];
    int s3 = col[e + 6];
    unsigned u0 = *(const unsigned*)(h + (size_t)s0 * 64 + cp * 2);
    unsigned u1 = *(const unsigned*)(h + (size_t)s1 * 64 + cp * 2);
    unsigned u2 = *(const unsigned*)(h + (size_t)s2 * 64 + cp * 2);
    unsigned u3 = *(const unsigned*)(h + (size_t)s3 * 64 + cp * 2);
    a0 += bf_lo(u0) + bf_lo(u1);
    a1 += bf_hi(u0) + bf_hi(u1);
    b0 += bf_lo(u2) + bf_lo(u3);
    b1 += bf_hi(u2) + bf_hi(u3);
  }
  for (; e < end; e += 2) {
    int s = col[e];
    unsigned u = *(const unsigned*)(h + (size_t)s * 64 + cp * 2);
    a0 += bf_lo(u);
    a1 += bf_hi(u);
  }
  a0 += b0;
  a1 += b1;
  a0 += __shfl_xor(a0, 32);
  a1 += __shfl_xor(a1, 32);

  float r0 = fmaxf(a0 + bias[cp * 2 + 0], 0.f);
  float r1 = fmaxf(a1 + bias[cp * 2 + 1], 0.f);
  if (lane < 32) {
    if constexpr (OUT_BF) {
      unsigned pack = (unsigned)(unsigned short)f2bf(r0) |
                      ((unsigned)(unsigned short)f2bf(r1) << 16);
      ((unsigned*)out)[(size_t)node * 32 + cp] = pack;
    } else {
      float2 v;
      v.x = r0;
      v.y = r1;
      ((float2*)out)[(size_t)node * 32 + cp] = v;
    }
  }
}

extern "C" void kernel_launch(void* const* d_in, const int* in_sizes, int n_in,
                              void* d_out, int out_size, void* d_ws,
                              size_t ws_size, hipStream_t stream) {
  const float* x = (const float*)d_in[0];
  const int* src = (const int*)d_in[1];
  const int* dst = (const int*)d_in[2];
  const float* W1 = (const float*)d_in[3];
  const float* b1 = (const float*)d_in[4];
  const float* W2 = (const float*)d_in[5];
  const float* b2 = (const float*)d_in[6];
  const float* W3 = (const float*)d_in[7];
  const float* b3 = (const float*)d_in[8];
  float* out = (float*)d_out;

  const int N = N_NODES_C;
  const int E = N_EDGES_C;

  // Workspace layout (44 MB; round 1 used 51.2 MB OK). NO overlaps now —
  // hist (cnt/rank) runs concurrently with gemm1 (hA).
  char* ws = (char*)d_ws;
  int* row_ptr = (int*)(ws + 0);               // [0, 1MB)
  int* col = (int*)(ws + (1u << 20));          // [1, 9MB)
  int* cnt = (int*)(ws + (9u << 20));          // [9, 10MB)
  int* bsum = (int*)(ws + (10u << 20));        // [10, 10.1MB)
  int* rank = (int*)(ws + (11u << 20));        // [11, 18MB)
  short* hA = (short*)(ws + (18u << 20));      // [18, 31MB)
  short* hB = (short*)(ws + (31u << 20));      // [31, 44MB)

  const int nb = (N + SCAN_B - 1) / SCAN_B;    // 391
  const int hist_grid = (E + 255) / 256;       // 6250
  const int gemm_grid = (N + 63) / 64;         // 1563
  const int fill_grid = (E / 4 + 255) / 256;   // 1563
  const int agg_grid = (N + 3) / 4;

  // ---- CSR build ∥ GEMM1 ----
  hipMemsetAsync(cnt, 0, (size_t)N * sizeof(int), stream);
  hist_gemm1_kernel<<<gemm_grid + hist_grid, 256, 0, stream>>>(
      x, W1, hA, N, gemm_grid, dst, cnt, rank, E);
  block_sum_kernel<<<nb, SCAN_B, 0, stream>>>(cnt, bsum, N);
  scan_bsums_kernel<<<1, 512, 0, stream>>>(bsum, nb);
  scan_final_kernel<<<nb, SCAN_B, 0, stream>>>(cnt, bsum, row_ptr, N, E);
  fill_kernel<<<fill_grid, 256, 0, stream>>>(src, dst, rank, row_ptr, col, E);

  // ---- Layer 1 agg: hB = bf16(relu(agg(hA) + b1)) ----
  agg64_kernel<true><<<agg_grid, 256, 0, stream>>>(hA, row_ptr, col, b1, hB, N);

  // ---- Layer 2 ----
  mfma_gemm64<64, true, true><<<gemm_grid, 256, 0, stream>>>(hB, W2, hA, N);
  agg64_kernel<true><<<agg_grid, 256, 0, stream>>>(hA, row_ptr, col, b2, hB, N);

  // ---- Layer 3 (fp32 out) ----
  mfma_gemm64<64, true, true><<<gemm_grid, 256, 0, stream>>>(hB, W3, hA, N);
  agg64_kernel<false><<<agg_grid, 256, 0, stream>>>(hA, row_ptr, col, b3, out, N);
}

// Round 6
// 300.365 us; speedup vs baseline: 4.5057x; 1.0162x over previous
//
#include <hip/hip_runtime.h>

#define N_NODES_C 100000
#define N_EDGES_C 1600000
#define SCAN_B 256

typedef short short8 __attribute__((ext_vector_type(8)));
typedef float f32x4 __attribute__((ext_vector_type(4)));

// float -> bf16 bits (RNE)
__device__ __forceinline__ short f2bf(float f) {
  unsigned u = __builtin_bit_cast(unsigned, f);
  unsigned r = (u + 0x7FFFu + ((u >> 16) & 1u)) >> 16;
  return (short)r;
}
// bf16 bits in low/high half of u32 -> float
__device__ __forceinline__ float bf_lo(unsigned u) {
  return __builtin_bit_cast(float, u << 16);
}
__device__ __forceinline__ float bf_hi(unsigned u) {
  return __builtin_bit_cast(float, u & 0xFFFF0000u);
}

// ---------------------------------------------------------------------------
// MFMA GEMM body: out[n][64] = in[n][K] @ W[K][64]
// 4 waves/block, each wave a 16x64 tile via 4 n-tiles of mfma 16x16x32_bf16.
// ---------------------------------------------------------------------------
template <int K, bool IN_BF, bool OUT_BF>
__device__ __forceinline__ void gemm64_body(
    int gblock, const void* __restrict__ in_, const float* __restrict__ W,
    void* __restrict__ out_, int n_rows) {
  constexpr int KS = K / 32;
  int wave = threadIdx.x >> 6;
  int lane = threadIdx.x & 63;
  int row0 = (gblock * 4 + wave) * 16;
  if (row0 >= n_rows) return;  // n_rows % 16 == 0 -> surviving tiles full

  int lrow = lane & 15;
  int lk = (lane >> 4) * 8;

  short8 bfrag[KS][4];
#pragma unroll
  for (int ks = 0; ks < KS; ++ks)
#pragma unroll
    for (int nt = 0; nt < 4; ++nt) {
      short8 b;
#pragma unroll
      for (int j = 0; j < 8; ++j)
        b[j] = f2bf(W[(size_t)(ks * 32 + lk + j) * 64 + nt * 16 + lrow]);
      bfrag[ks][nt] = b;
    }

  int row = row0 + lrow;
  f32x4 acc[4] = {};
#pragma unroll
  for (int ks = 0; ks < KS; ++ks) {
    short8 a;
    if constexpr (IN_BF) {
      const short* ip = (const short*)in_ + (size_t)row * K + ks * 32 + lk;
      a = *(const short8*)ip;
    } else {
      const float* ip = (const float*)in_ + (size_t)row * K + ks * 32 + lk;
      f32x4 v0 = *(const f32x4*)(ip);
      f32x4 v1 = *(const f32x4*)(ip + 4);
#pragma unroll
      for (int j = 0; j < 4; ++j) {
        a[j] = f2bf(v0[j]);
        a[4 + j] = f2bf(v1[j]);
      }
    }
#pragma unroll
    for (int nt = 0; nt < 4; ++nt)
      acc[nt] = __builtin_amdgcn_mfma_f32_16x16x32_bf16(a, bfrag[ks][nt],
                                                        acc[nt], 0, 0, 0);
  }

  int crow = row0 + (lane >> 4) * 4;
#pragma unroll
  for (int nt = 0; nt < 4; ++nt) {
    int ocol = nt * 16 + lrow;
#pragma unroll
    for (int r = 0; r < 4; ++r) {
      if constexpr (OUT_BF)
        ((short*)out_)[(size_t)(crow + r) * 64 + ocol] = f2bf(acc[nt][r]);
      else
        ((float*)out_)[(size_t)(crow + r) * 64 + ocol] = acc[nt][r];
    }
  }
}

template <int K, bool IN_BF, bool OUT_BF>
__global__ __launch_bounds__(256) void mfma_gemm64(
    const void* __restrict__ in_, const float* __restrict__ W,
    void* __restrict__ out_, int n_rows) {
  gemm64_body<K, IN_BF, OUT_BF>(blockIdx.x, in_, W, out_, n_rows);
}

// ---------------------------------------------------------------------------
// Fused: blocks [0, gemm_blocks) = GEMM1; rest = per-XCD privatized edge
// histogram. cnt8[xcc][N] with WORKGROUP-scope relaxed atomics: the RMW
// executes in the issuing XCD's own L2 (no device-scope write-through).
// Copy index = physical XCC_ID, so a given copy is only ever touched by
// blocks resident on that XCD -> single-L2 atomicity holds by construction.
// rank[i] = local_rank | (xcc << 24).
// ---------------------------------------------------------------------------
__global__ __launch_bounds__(256) void hist_gemm1_kernel(
    const float* __restrict__ x, const float* __restrict__ W1,
    short* __restrict__ hA, int n_rows, int gemm_blocks,
    const int* __restrict__ dst, int* __restrict__ cnt8, int* __restrict__ rank,
    int n_edges) {
  int b = (int)blockIdx.x;
  if (b < gemm_blocks) {
    gemm64_body<128, false, true>(b, x, W1, hA, n_rows);
    return;
  }
  int i = (b - gemm_blocks) * 256 + threadIdx.x;
  if (i >= n_edges) return;
  unsigned xcc;
  asm volatile("s_getreg_b32 %0, hwreg(HW_REG_XCC_ID)" : "=s"(xcc));
  xcc &= 7u;
  int d = dst[i];
  int lr = __hip_atomic_fetch_add(&cnt8[xcc * N_NODES_C + d], 1,
                                  __ATOMIC_RELAXED,
                                  __HIP_MEMORY_SCOPE_WORKGROUP);
  rank[i] = lr | (int)(xcc << 24);
}

// ---------------------------------------------------------------------------
// CSR build: scans over the 8 privatized histograms + atomic-free fill
// ---------------------------------------------------------------------------
__global__ __launch_bounds__(SCAN_B) void block_sum_kernel(
    const int* __restrict__ cnt8, int* __restrict__ bsum, int n) {
  __shared__ int lds[SCAN_B];
  int i = blockIdx.x * SCAN_B + threadIdx.x;
  int t = 0;
  if (i < n) {
#pragma unroll
    for (int xc = 0; xc < 8; ++xc) t += cnt8[xc * n + i];
  }
  lds[threadIdx.x] = t;
  __syncthreads();
  for (int s = SCAN_B / 2; s > 0; s >>= 1) {
    if (threadIdx.x < s) lds[threadIdx.x] += lds[threadIdx.x + s];
    __syncthreads();
  }
  if (threadIdx.x == 0) bsum[blockIdx.x] = lds[0];
}

__global__ __launch_bounds__(512) void scan_bsums_kernel(
    int* __restrict__ bsum, int nb) {
  __shared__ int lds[512];
  int v = (threadIdx.x < nb) ? bsum[threadIdx.x] : 0;
  lds[threadIdx.x] = v;
  __syncthreads();
  for (int off = 1; off < 512; off <<= 1) {
    int t = (threadIdx.x >= off) ? lds[threadIdx.x - off] : 0;
    __syncthreads();
    lds[threadIdx.x] += t;
    __syncthreads();
  }
  if (threadIdx.x < nb) bsum[threadIdx.x] = lds[threadIdx.x] - v;  // exclusive
}

// Per-node: total over 8 copies -> block-level exclusive scan -> row_ptr;
// also rewrites cnt8[xc][n] in place with the per-XCD exclusive prefix.
__global__ __launch_bounds__(SCAN_B) void scan_final_kernel(
    int* __restrict__ cnt8, const int* __restrict__ bsum,
    int* __restrict__ row_ptr, int n, int total) {
  __shared__ int lds[SCAN_B];
  int i = blockIdx.x * SCAN_B + threadIdx.x;
  int c[8];
  int v = 0;
  if (i < n) {
#pragma unroll
    for (int xc = 0; xc < 8; ++xc) {
      c[xc] = cnt8[xc * n + i];
      v += c[xc];
    }
  }
  lds[threadIdx.x] = v;
  __syncthreads();
  for (int off = 1; off < SCAN_B; off <<= 1) {
    int t = (threadIdx.x >= off) ? lds[threadIdx.x - off] : 0;
    __syncthreads();
    lds[threadIdx.x] += t;
    __syncthreads();
  }
  if (i < n) {
    int run = 0;
#pragma unroll
    for (int xc = 0; xc < 8; ++xc) {
      cnt8[xc * n + i] = run;  // px[xc][i]
      run += c[xc];
    }
    row_ptr[i] = lds[threadIdx.x] - v + bsum[blockIdx.x];
  }
  if (i == n - 1) row_ptr[n] = total;
}

// 4 edges/thread; pos = row_ptr[d] + px[xcc][d] + local_rank.
__global__ __launch_bounds__(256) void fill_kernel(
    const int* __restrict__ src, const int* __restrict__ dst,
    const int* __restrict__ rank, const int* __restrict__ row_ptr,
    const int* __restrict__ px, int* __restrict__ col, int n_edges) {
  int i4 = (blockIdx.x * 256 + threadIdx.x) * 4;
  if (i4 + 3 < n_edges) {
    int4 d = *(const int4*)(dst + i4);
    int4 r = *(const int4*)(rank + i4);
    int4 s = *(const int4*)(src + i4);
    col[row_ptr[d.x] + px[((unsigned)r.x >> 24) * N_NODES_C + d.x] +
        (r.x & 0xFFFFFF)] = s.x;
    col[row_ptr[d.y] + px[((unsigned)r.y >> 24) * N_NODES_C + d.y] +
        (r.y & 0xFFFFFF)] = s.y;
    col[row_ptr[d.z] + px[((unsigned)r.z >> 24) * N_NODES_C + d.z] +
        (r.z & 0xFFFFFF)] = s.z;
    col[row_ptr[d.w] + px[((unsigned)r.w >> 24) * N_NODES_C + d.w] +
        (r.w & 0xFFFFFF)] = s.w;
  } else {
    for (int i = i4; i < n_edges; ++i) {
      int d = dst[i];
      unsigned r = (unsigned)rank[i];
      col[row_ptr[d] + px[(r >> 24) * N_NODES_C + d] + (r & 0xFFFFFF)] = src[i];
    }
  }
}

// ---------------------------------------------------------------------------
// Pull aggregation + bias + ReLU. h bf16 [N][64]. Wave per node; lane =
// (edge-parity half) x (channel pair). 8 edges/iter, two accumulator pairs.
// ---------------------------------------------------------------------------
template <bool OUT_BF>
__global__ __launch_bounds__(256) void agg64_kernel(
    const short* __restrict__ h, const int* __restrict__ row_ptr,
    const int* __restrict__ col, const float* __restrict__ bias,
    void* __restrict__ out, int n_nodes) {
  int node = blockIdx.x * 4 + (threadIdx.x >> 6);
  if (node >= n_nodes) return;
  int lane = threadIdx.x & 63;
  int half = lane >> 5;
  int cp = lane & 31;

  int beg = row_ptr[node];
  int end = row_ptr[node + 1];
  float a0 = 0.f, a1 = 0.f, b0 = 0.f, b1 = 0.f;
  int e = beg + half;
  for (; e + 6 < end; e += 8) {
    int s0 = col[e];
    int s1 = col[e + 2];
    int s2 = col[e + 4];
    int s3 = col[e + 6];
    unsigned u0 = *(const unsigned*)(h + (size_t)s0 * 64 + cp * 2);
    unsigned u1 = *(const unsigned*)(h + (size_t)s1 * 64 + cp * 2);
    unsigned u2 = *(const unsigned*)(h + (size_t)s2 * 64 + cp * 2);
    unsigned u3 = *(const unsigned*)(h + (size_t)s3 * 64 + cp * 2);
    a0 += bf_lo(u0) + bf_lo(u1);
    a1 += bf_hi(u0) + bf_hi(u1);
    b0 += bf_lo(u2) + bf_lo(u3);
    b1 += bf_hi(u2) + bf_hi(u3);
  }
  for (; e < end; e += 2) {
    int s = col[e];
    unsigned u = *(const unsigned*)(h + (size_t)s * 64 + cp * 2);
    a0 += bf_lo(u);
    a1 += bf_hi(u);
  }
  a0 += b0;
  a1 += b1;
  a0 += __shfl_xor(a0, 32);
  a1 += __shfl_xor(a1, 32);

  float r0 = fmaxf(a0 + bias[cp * 2 + 0], 0.f);
  float r1 = fmaxf(a1 + bias[cp * 2 + 1], 0.f);
  if (lane < 32) {
    if constexpr (OUT_BF) {
      unsigned pack = (unsigned)(unsigned short)f2bf(r0) |
                      ((unsigned)(unsigned short)f2bf(r1) << 16);
      ((unsigned*)out)[(size_t)node * 32 + cp] = pack;
    } else {
      float2 v;
      v.x = r0;
      v.y = r1;
      ((float2*)out)[(size_t)node * 32 + cp] = v;
    }
  }
}

extern "C" void kernel_launch(void* const* d_in, const int* in_sizes, int n_in,
                              void* d_out, int out_size, void* d_ws,
                              size_t ws_size, hipStream_t stream) {
  const float* x = (const float*)d_in[0];
  const int* src = (const int*)d_in[1];
  const int* dst = (const int*)d_in[2];
  const float* W1 = (const float*)d_in[3];
  const float* b1 = (const float*)d_in[4];
  const float* W2 = (const float*)d_in[5];
  const float* b2 = (const float*)d_in[6];
  const float* W3 = (const float*)d_in[7];
  const float* b3 = (const float*)d_in[8];
  float* out = (float*)d_out;

  const int N = N_NODES_C;
  const int E = N_EDGES_C;

  // Workspace layout (47 MB). cnt8 = 8 privatized histograms (3.2 MB).
  char* ws = (char*)d_ws;
  int* row_ptr = (int*)(ws + 0);               // [0, 1MB)
  int* col = (int*)(ws + (1u << 20));          // [1, 9MB)
  int* cnt8 = (int*)(ws + (9u << 20));         // [9, 12.2MB)
  int* bsum = (int*)(ws + (13u << 20));        // [13, 13.1MB)
  int* rank = (int*)(ws + (14u << 20));        // [14, 20.4MB)
  short* hA = (short*)(ws + (21u << 20));      // [21, 34MB)
  short* hB = (short*)(ws + (34u << 20));      // [34, 47MB)

  const int nb = (N + SCAN_B - 1) / SCAN_B;    // 391
  const int hist_grid = (E + 255) / 256;       // 6250
  const int gemm_grid = (N + 63) / 64;         // 1563
  const int fill_grid = (E / 4 + 255) / 256;   // 1563
  const int agg_grid = (N + 3) / 4;

  // ---- CSR build ∥ GEMM1 ----
  hipMemsetAsync(cnt8, 0, (size_t)8 * N * sizeof(int), stream);
  hist_gemm1_kernel<<<gemm_grid + hist_grid, 256, 0, stream>>>(
      x, W1, hA, N, gemm_grid, dst, cnt8, rank, E);
  block_sum_kernel<<<nb, SCAN_B, 0, stream>>>(cnt8, bsum, N);
  scan_bsums_kernel<<<1, 512, 0, stream>>>(bsum, nb);
  scan_final_kernel<<<nb, SCAN_B, 0, stream>>>(cnt8, bsum, row_ptr, N, E);
  fill_kernel<<<fill_grid, 256, 0, stream>>>(src, dst, rank, row_ptr, cnt8,
                                             col, E);

  // ---- Layer 1 agg: hB = bf16(relu(agg(hA) + b1)) ----
  agg64_kernel<true><<<agg_grid, 256, 0, stream>>>(hA, row_ptr, col, b1, hB, N);

  // ---- Layer 2 ----
  mfma_gemm64<64, true, true><<<gemm_grid, 256, 0, stream>>>(hB, W2, hA, N);
  agg64_kernel<true><<<agg_grid, 256, 0, stream>>>(hA, row_ptr, col, b2, hB, N);

  // ---- Layer 3 (fp32 out) ----
  mfma_gemm64<64, true, true><<<gemm_grid, 256, 0, stream>>>(hB, W3, hA, N);
  agg64_kernel<false><<<agg_grid, 256, 0, stream>>>(hA, row_ptr, col, b3, out, N);
}